// Round 9
// baseline (73.671 us; speedup 1.0000x reference)
//
#include <hip/hip_runtime.h>
#include <hip/hip_bf16.h>
#include <math.h>

#define N_TOK 32768
#define DDIM 1024
#define NEXP 16
#define THREADS 256
#define TOK_PER_WAVE 16
#define TOK_PER_BLK 64
#define NBLK (N_TOK / TOK_PER_BLK)   // 512
#define KSTEPS (DDIM / 32)           // 32

typedef __attribute__((ext_vector_type(8))) short bf16x8;
typedef __attribute__((ext_vector_type(4))) float f32x4;

__device__ inline short f2bf(float f) {            // RNE f32->bf16 (inputs are normal)
    unsigned u = __builtin_bit_cast(unsigned, f);
    u += 0x7fffu + ((u >> 16) & 1u);
    return (short)(u >> 16);
}

// d_ws layout: [0,64) bytes: block-completion counter (zeroed each launch)
//              [64, 64 + NBLK*16*4): per-block load partials
// out layout (floats): [0,65536) top2 gates, [65536,131072) top2 indices (as float),
// [131072,131088) load
__global__ __launch_bounds__(THREADS, 2) void router_mfma(
    const float* __restrict__ x, const float* __restrict__ noise,
    const float* __restrict__ Wg, const float* __restrict__ Wn,
    float* __restrict__ out_gates, float* __restrict__ out_idx,
    float* __restrict__ partials, int* __restrict__ counter,
    float* __restrict__ out_load)
{
    // W fragments in LDS: slot = s*128 + tile*64 + lane' (4096 slots x 16B = 64 KB)
    // value at ushort idx slot*8+j = W_tile[lane'&15][s*32 + (lane'>>4)*8 + j] as bf16
    __shared__ unsigned short wlds[32768];
    __shared__ float blk_load[NEXP];
    __shared__ int isLast;

    const int tid  = threadIdx.x;
    const int lane = tid & 63;

    // ---- stage W -> LDS (stride-1 slots: conflict-free b128 writes) ----
#pragma unroll
    for (int cc = 0; cc < 16; ++cc) {
        const int slot  = cc * 256 + tid;
        const int laneP = slot & 63;
        const int tile  = (slot >> 6) & 1;
        const int s     = slot >> 7;
        const int m     = laneP & 15;
        const int half  = laneP >> 4;
        const int k0    = s * 32 + half * 8;
        const float* Wsrc = (tile ? Wn : Wg) + (size_t)m * DDIM + k0;
        const float4 f0 = *(const float4*)Wsrc;
        const float4 f1 = *(const float4*)(Wsrc + 4);
        bf16x8 v;
        v[0] = f2bf(f0.x); v[1] = f2bf(f0.y); v[2] = f2bf(f0.z); v[3] = f2bf(f0.w);
        v[4] = f2bf(f1.x); v[5] = f2bf(f1.y); v[6] = f2bf(f1.z); v[7] = f2bf(f1.w);
        *(bf16x8*)&wlds[(size_t)slot * 8] = v;
    }
    if (tid < NEXP) blk_load[tid] = 0.0f;
    __syncthreads();

    const int w   = tid >> 6;
    const int tok = blockIdx.x * TOK_PER_BLK + w * TOK_PER_WAVE + (lane & 15);
    const int grp = lane >> 4;                       // 4-lane group id for this token

    const float* xb = x + (size_t)tok * DDIM + grp * 8;

    f32x4 acc0 = {0.f, 0.f, 0.f, 0.f};              // D rows: gate logits
    f32x4 acc1 = {0.f, 0.f, 0.f, 0.f};              // D rows: noise logits

    // ---- K loop: 4 windows of 8 k-steps, 2-deep register ping-pong on x ----
#define LOAD_WIN(BUF, WI) do { _Pragma("unroll") \
    for (int i = 0; i < 8; ++i) { \
        BUF[2*i]   = *(const float4*)(xb + ((WI)*8 + i) * 32); \
        BUF[2*i+1] = *(const float4*)(xb + ((WI)*8 + i) * 32 + 4); \
    } } while (0)

#define CONS_WIN(BUF, WI) do { _Pragma("unroll") \
    for (int i = 0; i < 8; ++i) { \
        const int s_ = (WI)*8 + i; \
        const bf16x8 a0 = *(const bf16x8*)&wlds[(size_t)(s_*2 + 0) * 512 + lane * 8]; \
        const bf16x8 a1 = *(const bf16x8*)&wlds[(size_t)(s_*2 + 1) * 512 + lane * 8]; \
        bf16x8 b; \
        b[0] = f2bf(BUF[2*i].x);   b[1] = f2bf(BUF[2*i].y); \
        b[2] = f2bf(BUF[2*i].z);   b[3] = f2bf(BUF[2*i].w); \
        b[4] = f2bf(BUF[2*i+1].x); b[5] = f2bf(BUF[2*i+1].y); \
        b[6] = f2bf(BUF[2*i+1].z); b[7] = f2bf(BUF[2*i+1].w); \
        acc0 = __builtin_amdgcn_mfma_f32_16x16x32_bf16(a0, b, acc0, 0, 0, 0); \
        acc1 = __builtin_amdgcn_mfma_f32_16x16x32_bf16(a1, b, acc1, 0, 0, 0); \
    } } while (0)

    float4 XA[16], XB[16];
    LOAD_WIN(XA, 0);
    LOAD_WIN(XB, 1);
    CONS_WIN(XA, 0);  LOAD_WIN(XA, 2);
    CONS_WIN(XB, 1);  LOAD_WIN(XB, 3);
    CONS_WIN(XA, 2);
    CONS_WIN(XB, 3);

    // ---- epilogue: lane holds experts e = grp*4 + r for token tok ----
    const float4 nz4 = *(const float4*)(noise + (size_t)tok * NEXP + grp * 4);
    const float nzv[4] = {nz4.x, nz4.y, nz4.z, nz4.w};

    float lg[4];
#pragma unroll
    for (int r = 0; r < 4; ++r) {
        const float cl = acc0[r];
        const float nl = acc1[r];
        const float sp = fmaxf(nl, 0.0f) + log1pf(expf(-fabsf(nl)));
        lg[r] = cl + nzv[r] * sp * 0.01f;
    }

    float m = fmaxf(fmaxf(lg[0], lg[1]), fmaxf(lg[2], lg[3]));
    m = fmaxf(m, __shfl_xor(m, 16, 64));
    m = fmaxf(m, __shfl_xor(m, 32, 64));

    float p[4];
    float ssum = 0.0f;
#pragma unroll
    for (int r = 0; r < 4; ++r) { p[r] = expf(lg[r] - m); ssum += p[r]; }
    ssum += __shfl_xor(ssum, 16, 64);
    ssum += __shfl_xor(ssum, 32, 64);
    const float inv = 1.0f / ssum;

    float g[4];
#pragma unroll
    for (int r = 0; r < 4; ++r) g[r] = p[r] * inv;

    // local top-2 (tie -> lower index), then butterfly merge across 4 lanes
    float v1 = -1.0f, v2 = -1.0f;
    int   i1 = 0,     i2 = 0;
#pragma unroll
    for (int r = 0; r < 4; ++r) {
        const float ge = g[r];
        const int   e  = grp * 4 + r;
        if (ge > v1)      { v2 = v1; i2 = i1; v1 = ge; i1 = e; }
        else if (ge > v2) { v2 = ge; i2 = e; }
    }
#pragma unroll
    for (int off = 16; off <= 32; off <<= 1) {
        const float ov1 = __shfl_xor(v1, off, 64);
        const float ov2 = __shfl_xor(v2, off, 64);
        const int   oi1 = __shfl_xor(i1, off, 64);
        const int   oi2 = __shfl_xor(i2, off, 64);
        const bool aWins = (v1 > ov1) || (v1 == ov1 && i1 < oi1);
        float nv1, nv2; int ni1, ni2;
        if (aWins) {
            nv1 = v1; ni1 = i1;
            const bool bNext = (ov1 > v2) || (ov1 == v2 && oi1 < i2);
            nv2 = bNext ? ov1 : v2;  ni2 = bNext ? oi1 : i2;
        } else {
            nv1 = ov1; ni1 = oi1;
            const bool aNext = (v1 > ov2) || (v1 == ov2 && i1 < oi2);
            nv2 = aNext ? v1 : ov2;  ni2 = aNext ? i1 : oi2;
        }
        v1 = nv1; v2 = nv2; i1 = ni1; i2 = ni2;
    }
    if (grp == 0) {
        const float den = v1 + v2 + 1e-8f;
        out_gates[(size_t)tok * 2 + 0] = v1 / den;
        out_gates[(size_t)tok * 2 + 1] = v2 / den;
        out_idx[(size_t)tok * 2 + 0] = (float)i1;
        out_idx[(size_t)tok * 2 + 1] = (float)i2;
    }

    // ---- load partials (block-local) ----
#pragma unroll
    for (int r = 0; r < 4; ++r) {
        float v = g[r];
        v += __shfl_xor(v, 1, 64);
        v += __shfl_xor(v, 2, 64);
        v += __shfl_xor(v, 4, 64);
        v += __shfl_xor(v, 8, 64);
        if ((lane & 15) == 0) atomicAdd(&blk_load[grp * 4 + r], v);
    }
    __syncthreads();
    if (tid < NEXP) partials[(size_t)blockIdx.x * NEXP + tid] = blk_load[tid];

    // ---- last-block global reduction of load ----
    __threadfence();                 // writers (tid<16) push partials to device scope
    __syncthreads();                 // all fences retired before the count
    if (tid == 0) {
        const int old = atomicAdd(counter, 1);
        isLast = (old == NBLK - 1);
    }
    __syncthreads();
    if (isLast) {
        __threadfence();             // acquire side: see all blocks' partials
        if (tid < 64) {
            float loc[16];
#pragma unroll
            for (int e = 0; e < 16; ++e) loc[e] = 0.0f;
            for (int b = tid; b < NBLK; b += 64) {
                const float4* pp = (const float4*)(partials + (size_t)b * 16);
#pragma unroll
                for (int j = 0; j < 4; ++j) {
                    const float4 v = pp[j];
                    loc[j * 4 + 0] += v.x; loc[j * 4 + 1] += v.y;
                    loc[j * 4 + 2] += v.z; loc[j * 4 + 3] += v.w;
                }
            }
#pragma unroll
            for (int e = 0; e < 16; ++e) {
                float v = loc[e];
#pragma unroll
                for (int off = 32; off; off >>= 1) v += __shfl_xor(v, off, 64);
                if (tid == 0) out_load[e] = v;
            }
        }
    }
#undef LOAD_WIN
#undef CONS_WIN
}

extern "C" void kernel_launch(void* const* d_in, const int* in_sizes, int n_in,
                              void* d_out, int out_size, void* d_ws, size_t ws_size,
                              hipStream_t stream) {
    (void)in_sizes; (void)n_in; (void)ws_size; (void)out_size;
    const float* x     = (const float*)d_in[0];
    const float* noise = (const float*)d_in[1];
    const float* Wg    = (const float*)d_in[2];
    const float* Wn    = (const float*)d_in[3];

    float* out       = (float*)d_out;
    float* out_gates = out;
    float* out_idx   = out + (size_t)N_TOK * 2;
    float* out_load  = out + (size_t)N_TOK * 4;

    int*   counter  = (int*)d_ws;                       // [0,64) bytes
    float* partials = (float*)((char*)d_ws + 64);       // NBLK*16 floats

    hipMemsetAsync(d_ws, 0, 64, stream);                // zero the counter
    router_mfma<<<NBLK, THREADS, 0, stream>>>(
        x, noise, Wg, Wn, out_gates, out_idx, partials, counter, out_load);
}